// Round 3
// baseline (29.367 us; speedup 1.0000x reference)
//
#include <hip/hip_runtime.h>

// out[b][i][j][k] = ah[b][i] * vh[b][j] * th[b][k], ah/vh/th = [1, row].
// B=128, D=63 -> padded 64. Flat layout: (((b*64)+i)*64+j)*64+k.
// Store-BW-bound: 134 MB fp32 out. Each block writes 4 i-slabs (64 KB
// contiguous) to amortize the LDS prologue; stores are non-temporal.

typedef float f4 __attribute__((ext_vector_type(4)));  // native vec for nt-store

__global__ __launch_bounds__(256) void tensorFusion_kernel(
    const float* __restrict__ t,
    const float* __restrict__ a,
    const float* __restrict__ v,
    float* __restrict__ out)
{
    const int D   = 63;
    const int blk = blockIdx.x;        // 0..2047
    const int b   = blk >> 4;          // batch
    const int i0  = (blk & 15) << 2;   // first of 4 consecutive i values

    __shared__ float vh[64];
    __shared__ float th[64];
    __shared__ float ah[64];

    const int tid = threadIdx.x;
    if (tid < 64) {
        vh[tid] = (tid == 0) ? 1.0f : v[b * D + tid - 1];
        th[tid] = (tid == 0) ? 1.0f : t[b * D + tid - 1];
        ah[tid] = (tid == 0) ? 1.0f : a[b * D + tid - 1];
    }
    __syncthreads();

    const float a0 = ah[i0 + 0];
    const float a1 = ah[i0 + 1];
    const float a2 = ah[i0 + 2];
    const float a3 = ah[i0 + 3];

    const f4* __restrict__ th4 = reinterpret_cast<const f4*>(th);
    // Block's slab: 4 consecutive i planes of batch b, 4*4096 floats contiguous.
    f4* __restrict__ outp =
        reinterpret_cast<f4*>(out) + ((size_t)b * 64 + i0) * 1024;

    #pragma unroll
    for (int pass = 0; pass < 4; ++pass) {
        const int idx = pass * 256 + tid;     // float4 index within one i-slab
        const float vj = vh[idx >> 4];        // j = (idx*4)>>6
        const f4    tk = th4[idx & 15];       // th[k..k+3], k = (idx*4)&63

        __builtin_nontemporal_store((a0 * vj) * tk, &outp[0 * 1024 + idx]);
        __builtin_nontemporal_store((a1 * vj) * tk, &outp[1 * 1024 + idx]);
        __builtin_nontemporal_store((a2 * vj) * tk, &outp[2 * 1024 + idx]);
        __builtin_nontemporal_store((a3 * vj) * tk, &outp[3 * 1024 + idx]);
    }
}

extern "C" void kernel_launch(void* const* d_in, const int* in_sizes, int n_in,
                              void* d_out, int out_size, void* d_ws, size_t ws_size,
                              hipStream_t stream) {
    const float* t = (const float*)d_in[0];
    const float* a = (const float*)d_in[1];
    const float* v = (const float*)d_in[2];
    float* out = (float*)d_out;

    // 128 batches * 16 i-groups = 2048 blocks, each writes 64 KB contiguous.
    tensorFusion_kernel<<<dim3(128 * 16), dim3(256), 0, stream>>>(t, a, v, out);
}

// Round 4
// 25.453 us; speedup vs baseline: 1.1538x; 1.1538x over previous
//
#include <hip/hip_runtime.h>

// out[b][i][j][k] = ah[b][i] * vh[b][j] * th[b][k], ah/vh/th = [1, row].
// B=128, D=63 -> padded 64. Flat layout: (((b*64)+i)*64+j)*64+k.
// Store-BW-bound: 134 MB fp32 out. Each block writes 4 i-slabs (64 KB
// contiguous). Plain (cached) stores — nt stores regressed 25.9->29.4 us
// in round 3 (nt bypasses L2 write aggregation).

__global__ __launch_bounds__(256) void tensorFusion_kernel(
    const float* __restrict__ t,
    const float* __restrict__ a,
    const float* __restrict__ v,
    float* __restrict__ out)
{
    const int D   = 63;
    const int blk = blockIdx.x;        // 0..2047
    const int b   = blk >> 4;          // batch
    const int i0  = (blk & 15) << 2;   // first of 4 consecutive i values

    __shared__ float vh[64];
    __shared__ float th[64];
    __shared__ float ah[64];

    const int tid = threadIdx.x;
    if (tid < 64) {
        vh[tid] = (tid == 0) ? 1.0f : v[b * D + tid - 1];
        th[tid] = (tid == 0) ? 1.0f : t[b * D + tid - 1];
        ah[tid] = (tid == 0) ? 1.0f : a[b * D + tid - 1];
    }
    __syncthreads();

    const float a0 = ah[i0 + 0];
    const float a1 = ah[i0 + 1];
    const float a2 = ah[i0 + 2];
    const float a3 = ah[i0 + 3];

    const float4* __restrict__ th4 = reinterpret_cast<const float4*>(th);
    // Block's slab: 4 consecutive i planes of batch b, 4*4096 floats contiguous.
    float4* __restrict__ outp =
        reinterpret_cast<float4*>(out) + ((size_t)b * 64 + i0) * 1024;

    #pragma unroll
    for (int pass = 0; pass < 4; ++pass) {
        const int idx = pass * 256 + tid;     // float4 index within one i-slab
        const float  vj = vh[idx >> 4];       // j = (idx*4)>>6
        const float4 tk = th4[idx & 15];      // th[k..k+3], k = (idx*4)&63

        const float s0 = a0 * vj;
        const float s1 = a1 * vj;
        const float s2 = a2 * vj;
        const float s3 = a3 * vj;

        outp[0 * 1024 + idx] = make_float4(s0 * tk.x, s0 * tk.y, s0 * tk.z, s0 * tk.w);
        outp[1 * 1024 + idx] = make_float4(s1 * tk.x, s1 * tk.y, s1 * tk.z, s1 * tk.w);
        outp[2 * 1024 + idx] = make_float4(s2 * tk.x, s2 * tk.y, s2 * tk.z, s2 * tk.w);
        outp[3 * 1024 + idx] = make_float4(s3 * tk.x, s3 * tk.y, s3 * tk.z, s3 * tk.w);
    }
}

extern "C" void kernel_launch(void* const* d_in, const int* in_sizes, int n_in,
                              void* d_out, int out_size, void* d_ws, size_t ws_size,
                              hipStream_t stream) {
    const float* t = (const float*)d_in[0];
    const float* a = (const float*)d_in[1];
    const float* v = (const float*)d_in[2];
    float* out = (float*)d_out;

    // 128 batches * 16 i-groups = 2048 blocks, each writes 64 KB contiguous.
    tensorFusion_kernel<<<dim3(128 * 16), dim3(256), 0, stream>>>(t, a, v, out);
}